// Round 7
// baseline (1107.483 us; speedup 1.0000x reference)
//
#include <hip/hip_runtime.h>

#define CH 64
#define BN_EPS 1e-5f
#define DPB 8   // dst nodes per block in the edge kernel

typedef __attribute__((ext_vector_type(8))) __bf16 bf16x8;
typedef __attribute__((ext_vector_type(4))) __bf16 bf16x4;
typedef __attribute__((ext_vector_type(4))) float f32x4;

__device__ __forceinline__ float silu_f(float x) { return x / (1.0f + __expf(-x)); }

// ---------------------------------------------------------------------------
// Kernel: h = x @ Win + bin ; accumulate per-channel sum/sumsq for BN1
// ---------------------------------------------------------------------------
__global__ __launch_bounds__(256) void k_lin_in(
    const float* __restrict__ x, const float* __restrict__ Win, const float* __restrict__ bin,
    float* __restrict__ h, float* __restrict__ ssum, float* __restrict__ ssq, int N)
{
    __shared__ float xt[64 * 64];
    __shared__ float Wl[64 * 64];
    __shared__ float red[2][4][64];
    const int t = threadIdx.x, c = t & 63, g = t >> 6;
    const int row0 = blockIdx.x * 64;

    for (int i = t; i < 64 * 64; i += 256) {
        int r = i >> 6, cc = i & 63;
        int gr = row0 + r;
        xt[i] = (gr < N) ? x[(size_t)gr * CH + cc] : 0.0f;
        Wl[i] = Win[i];
    }
    __syncthreads();

    float acc[16];
    const float b = bin[c];
#pragma unroll
    for (int i = 0; i < 16; ++i) acc[i] = b;
    for (int k = 0; k < 64; ++k) {
        float w = Wl[k * 64 + c];
#pragma unroll
        for (int i = 0; i < 16; ++i) acc[i] += xt[(g * 16 + i) * 64 + k] * w;
    }
    float s = 0.0f, ss = 0.0f;
#pragma unroll
    for (int i = 0; i < 16; ++i) {
        int gr = row0 + g * 16 + i;
        if (gr < N) {
            h[(size_t)gr * CH + c] = acc[i];
            s += acc[i];
            ss += acc[i] * acc[i];
        }
    }
    red[0][g][c] = s;
    red[1][g][c] = ss;
    __syncthreads();
    if (g == 0) {
        atomicAdd(&ssum[c], red[0][0][c] + red[0][1][c] + red[0][2][c] + red[0][3][c]);
        atomicAdd(&ssq[c],  red[1][0][c] + red[1][1][c] + red[1][2][c] + red[1][3][c]);
    }
}

// ---------------------------------------------------------------------------
__global__ void k_stats(const float* __restrict__ ssum, const float* __restrict__ ssq,
                        const float* __restrict__ gamma, const float* __restrict__ beta,
                        float* __restrict__ scale, float* __restrict__ shift, int N)
{
    int c = threadIdx.x;
    float inv = 1.0f / (float)N;
    float mu = ssum[c] * inv;
    float var = ssq[c] * inv - mu * mu;
    float sc = gamma[c] * rsqrtf(var + BN_EPS);
    scale[c] = sc;
    shift[c] = beta[c] - mu * sc;
}

// ---------------------------------------------------------------------------
// Kernel: x1 = silu(h*scale+shift); v/k/q = x1@W — stored as bf16
// ---------------------------------------------------------------------------
__global__ __launch_bounds__(256) void k_vkq(
    const float* __restrict__ h, const float* __restrict__ scale, const float* __restrict__ shift,
    const float* __restrict__ Wv, const float* __restrict__ Wk, const float* __restrict__ Wq,
    __bf16* __restrict__ vv, __bf16* __restrict__ kk, __bf16* __restrict__ qq, int N)
{
    __shared__ float xt[64 * 64];
    __shared__ float Wl[2][64 * 64];
    const int t = threadIdx.x, c = t & 63, g = t >> 6;
    const int row0 = blockIdx.x * 64;

    for (int i = t; i < 64 * 64; i += 256) {
        int r = i >> 6, cc = i & 63;
        int gr = row0 + r;
        float hv = (gr < N) ? h[(size_t)gr * CH + cc] : 0.0f;
        xt[i] = silu_f(hv * scale[cc] + shift[cc]);
        Wl[0][i] = Wv[i];
        Wl[1][i] = Wk[i];
    }
    __syncthreads();

    for (int m = 0; m < 2; ++m) {
        float acc[16];
#pragma unroll
        for (int i = 0; i < 16; ++i) acc[i] = 0.0f;
        for (int k = 0; k < 64; ++k) {
            float w = Wl[m][k * 64 + c];
#pragma unroll
            for (int i = 0; i < 16; ++i) acc[i] += xt[(g * 16 + i) * 64 + k] * w;
        }
        __bf16* o = (m == 0) ? vv : kk;
#pragma unroll
        for (int i = 0; i < 16; ++i) {
            int gr = row0 + g * 16 + i;
            if (gr < N) o[(size_t)gr * CH + c] = (__bf16)acc[i];
        }
    }
    __syncthreads();
    for (int i = t; i < 64 * 64; i += 256) Wl[0][i] = Wq[i];
    __syncthreads();
    {
        float acc[16];
#pragma unroll
        for (int i = 0; i < 16; ++i) acc[i] = 0.0f;
        for (int k = 0; k < 64; ++k) {
            float w = Wl[0][k * 64 + c];
#pragma unroll
            for (int i = 0; i < 16; ++i) acc[i] += xt[(g * 16 + i) * 64 + k] * w;
        }
#pragma unroll
        for (int i = 0; i < 16; ++i) {
            int gr = row0 + g * 16 + i;
            if (gr < N) qq[(size_t)gr * CH + c] = (__bf16)acc[i];
        }
    }
}

// ---------------------------------------------------------------------------
// Counting sort by dst: hist -> 2-level exclusive scan -> scatter (int2)
// ---------------------------------------------------------------------------
__global__ void k_hist(const int* __restrict__ dstA, int* __restrict__ cnt, int E, int Etot)
{
    int e = blockIdx.x * blockDim.x + threadIdx.x;
    if (e < Etot) {
        int d = (e < E) ? dstA[e] : (e - E);
        atomicAdd(&cnt[d], 1);
    }
}

__global__ __launch_bounds__(256) void k_scan_a(
    const int* __restrict__ cnt, int* __restrict__ exc, int* __restrict__ bsum, int N)
{
    __shared__ int sh[256];
    const int b = blockIdx.x, t = threadIdx.x;
    const int base = b * 1024 + t * 4;
    int v0 = (base + 0 < N) ? cnt[base + 0] : 0;
    int v1 = (base + 1 < N) ? cnt[base + 1] : 0;
    int v2 = (base + 2 < N) ? cnt[base + 2] : 0;
    int v3 = (base + 3 < N) ? cnt[base + 3] : 0;
    int s = v0 + v1 + v2 + v3;
    sh[t] = s;
    __syncthreads();
    for (int off = 1; off < 256; off <<= 1) {
        int x = (t >= off) ? sh[t - off] : 0;
        __syncthreads();
        sh[t] += x;
        __syncthreads();
    }
    int p = sh[t] - s;
    if (t == 255) bsum[b] = sh[255];
    if (base + 0 < N) exc[base + 0] = p; p += v0;
    if (base + 1 < N) exc[base + 1] = p; p += v1;
    if (base + 2 < N) exc[base + 2] = p; p += v2;
    if (base + 3 < N) exc[base + 3] = p;
}

__global__ __launch_bounds__(256) void k_scan_b(int* __restrict__ bsum, int nb)
{
    __shared__ int sh[256];
    const int t = threadIdx.x;
    int v = (t < nb) ? bsum[t] : 0;
    sh[t] = v;
    __syncthreads();
    for (int off = 1; off < 256; off <<= 1) {
        int x = (t >= off) ? sh[t - off] : 0;
        __syncthreads();
        sh[t] += x;
        __syncthreads();
    }
    if (t < nb) bsum[t] = sh[t] - v;
}

__global__ void k_scan_c(const int* __restrict__ exc, const int* __restrict__ bsum,
                         int* __restrict__ rowptr, int* __restrict__ cur, int N)
{
    int i = blockIdx.x * blockDim.x + threadIdx.x;
    if (i < N) {
        int r = exc[i] + bsum[i >> 10];
        rowptr[i] = r;
        cur[i] = r;
    }
}

__global__ void k_scatter(const int* __restrict__ srcA, const int* __restrict__ dstA,
                          int* __restrict__ cur, int2* __restrict__ sortedSD, int E, int Etot)
{
    int e = blockIdx.x * blockDim.x + threadIdx.x;
    if (e < Etot) {
        int d, s;
        if (e < E) { d = dstA[e]; s = srcA[e]; }
        else       { d = s = e - E; }
        int p = atomicAdd(&cur[d], 1);
        sortedSD[p] = make_int2(s, d);
    }
}

// ---------------------------------------------------------------------------
// Edge kernel: each block owns DPB consecutive dst nodes; processes their
// sorted edges in 16-edge MFMA windows; accumulates den/num in LDS via
// ds_add_f32 (NO global atomics); writes pre = num/den once at the end.
// ---------------------------------------------------------------------------
__global__ __launch_bounds__(256) void k_edge_grp(
    const int2* __restrict__ sortedSD, const int* __restrict__ rowptr,
    const float* __restrict__ pos,
    const __bf16* __restrict__ vvb, const __bf16* __restrict__ kkb, const __bf16* __restrict__ qqb,
    const float* __restrict__ P1, const float* __restrict__ pb1,
    const float* __restrict__ P2, const float* __restrict__ pb2,
    const float* __restrict__ A1, const float* __restrict__ ab1,
    const float* __restrict__ A2, const float* __restrict__ ab2,
    float* __restrict__ pre, int N, int Etot)
{
    __shared__ __align__(16) __bf16 Wtab[3][8][64][8];   // 24.0 KiB
    __shared__ __align__(16) __bf16 tb[4][16][66];       //  8.25 KiB
    __shared__ __align__(16) __bf16 P1L[3][64];          //  384 B
    __shared__ __align__(16) float pb1L[64];             //  256 B
    __shared__ float accS[2][DPB][64];                   //  4.0 KiB

    const int t = threadIdx.x;
    for (int i = t; i < 3 * 4096; i += 256) {
        int mat = i >> 12, r = i & 4095;
        int j = r & 7, lane = (r >> 3) & 63, ksnt = r >> 9;
        int ks = ksnt & 1, nt = ksnt >> 1;
        int k = ks * 32 + ((lane >> 4) & 3) * 8 + j;
        int n = nt * 16 + (lane & 15);
        const float* W = (mat == 0) ? P2 : ((mat == 1) ? A1 : A2);
        Wtab[mat][ksnt][lane][j] = (__bf16)W[k * 64 + n];
    }
    if (t < 192) P1L[t / 64][t & 63] = (__bf16)P1[t];
    if (t < 64)  pb1L[t] = pb1[t];
#pragma unroll
    for (int i = t; i < 2 * DPB * 64; i += 256) ((float*)accS)[i] = 0.0f;
    __syncthreads();

    const int l = t & 63, wid = t >> 6, lg = l >> 4, lm = l & 15;
    __bf16* tbw = &tb[wid][0][0];

    float pb2r[4], ab1r[4], ab2r[4];
#pragma unroll
    for (int nt = 0; nt < 4; ++nt) {
        int co = nt * 16 + lm;
        pb2r[nt] = pb2[co];
        ab1r[nt] = ab1[co]; ab2r[nt] = ab2[co];
    }

    const int D0 = blockIdx.x * DPB;
    const int R0 = rowptr[D0];
    const int R1 = (D0 + DPB >= N) ? Etot : rowptr[D0 + DPB];
    const int nE = R1 - R0;

    for (int win = wid; win * 16 < nE; win += 4) {
        const int eBase = R0 + win * 16;
        const int eA = eBase + lm;
        int sC = 0, dloc = 0;
        int dC = D0;
        if (eA < R1) {
            int2 sd = sortedSD[eA];
            sC = sd.x; dC = sd.y;
            dloc = dC - D0;
        }

        // ---- gathers
        const float* ps = pos + (size_t)sC * 3;
        const float* pd = pos + (size_t)dC * 3;
        float pdl0 = pd[0] - ps[0], pdl1 = pd[1] - ps[1], pdl2 = pd[2] - ps[2];
        const __bf16* qp = qqb + (size_t)dC * 64 + lg * 8;
        const __bf16* kp = kkb + (size_t)sC * 64 + lg * 8;
        bf16x8 q0 = *(const bf16x8*)qp, q1 = *(const bf16x8*)(qp + 32);
        bf16x8 k0 = *(const bf16x8*)kp, k1 = *(const bf16x8*)(kp + 32);
        bf16x8 qmk0, qmk1;
#pragma unroll
        for (int j = 0; j < 8; ++j) {
            qmk0[j] = (__bf16)((float)q0[j] - (float)k0[j]);
            qmk1[j] = (__bf16)((float)q1[j] - (float)k1[j]);
        }
        int dlocD[4];
        __bf16 vcur[4][4];
#pragma unroll
        for (int jj = 0; jj < 4; ++jj) {
            int sD = __shfl(sC, lg * 4 + jj);
            dlocD[jj] = __shfl(dloc, lg * 4 + jj);
            const __bf16* vp = vvb + (size_t)sD * 64 + lm;
#pragma unroll
            for (int nt = 0; nt < 4; ++nt) vcur[jj][nt] = vp[nt * 16];
        }

        // ---- P1 layer on VALU, directly in A-layout (edge row = lm = own lane)
        bf16x8 aX0, aX1;
#pragma unroll
        for (int f = 0; f < 2; ++f) {
            const int k0i = f * 32 + lg * 8;
            bf16x8 w0 = *(const bf16x8*)&P1L[0][k0i];
            bf16x8 w1 = *(const bf16x8*)&P1L[1][k0i];
            bf16x8 w2 = *(const bf16x8*)&P1L[2][k0i];
            f32x4 b0 = *(const f32x4*)&pb1L[k0i];
            f32x4 b1 = *(const f32x4*)&pb1L[k0i + 4];
#pragma unroll
            for (int j = 0; j < 8; ++j) {
                float bb = (j < 4) ? b0[j & 3] : b1[j & 3];
                float tv = silu_f(pdl0 * (float)w0[j] + pdl1 * (float)w1[j] +
                                  pdl2 * (float)w2[j] + bb);
                if (f == 0) aX0[j] = (__bf16)tv; else aX1[j] = (__bf16)tv;
            }
        }

        // ---- P2
        f32x4 acc[4];
#pragma unroll
        for (int nt = 0; nt < 4; ++nt) {
            f32x4 a; a[0] = a[1] = a[2] = a[3] = pb2r[nt];
            a = __builtin_amdgcn_mfma_f32_16x16x32_bf16(aX0, *(const bf16x8*)&Wtab[0][nt * 2 + 0][l][0], a, 0, 0, 0);
            a = __builtin_amdgcn_mfma_f32_16x16x32_bf16(aX1, *(const bf16x8*)&Wtab[0][nt * 2 + 1][l][0], a, 0, 0, 0);
            acc[nt] = a;
        }
        bf16x4 dltb[4];
#pragma unroll
        for (int nt = 0; nt < 4; ++nt)
#pragma unroll
            for (int jj = 0; jj < 4; ++jj) {
                float dv = silu_f(acc[nt][jj]);
                dltb[nt][jj] = (__bf16)dv;
                tbw[(lg * 4 + jj) * 66 + nt * 16 + lm] = (__bf16)dv;
            }

        // ---- alpha0 = (q-k) + delta  (delta re-read in A-layout)
        bf16x8 dA0 = *(const bf16x8*)&tbw[lm * 66 + lg * 8];
        bf16x8 dA1 = *(const bf16x8*)&tbw[lm * 66 + 32 + lg * 8];
        bf16x8 aA0, aA1;
#pragma unroll
        for (int j = 0; j < 8; ++j) {
            aA0[j] = (__bf16)((float)qmk0[j] + (float)dA0[j]);
            aA1[j] = (__bf16)((float)qmk1[j] + (float)dA1[j]);
        }

        // ---- A1
#pragma unroll
        for (int nt = 0; nt < 4; ++nt) {
            f32x4 a; a[0] = a[1] = a[2] = a[3] = ab1r[nt];
            a = __builtin_amdgcn_mfma_f32_16x16x32_bf16(aA0, *(const bf16x8*)&Wtab[1][nt * 2 + 0][l][0], a, 0, 0, 0);
            a = __builtin_amdgcn_mfma_f32_16x16x32_bf16(aA1, *(const bf16x8*)&Wtab[1][nt * 2 + 1][l][0], a, 0, 0, 0);
            acc[nt] = a;
        }
#pragma unroll
        for (int nt = 0; nt < 4; ++nt)
#pragma unroll
            for (int jj = 0; jj < 4; ++jj)
                tbw[(lg * 4 + jj) * 66 + nt * 16 + lm] = (__bf16)silu_f(acc[nt][jj]);
        bf16x8 aY0 = *(const bf16x8*)&tbw[lm * 66 + lg * 8];
        bf16x8 aY1 = *(const bf16x8*)&tbw[lm * 66 + 32 + lg * 8];

        // ---- A2
#pragma unroll
        for (int nt = 0; nt < 4; ++nt) {
            f32x4 a; a[0] = a[1] = a[2] = a[3] = ab2r[nt];
            a = __builtin_amdgcn_mfma_f32_16x16x32_bf16(aY0, *(const bf16x8*)&Wtab[2][nt * 2 + 0][l][0], a, 0, 0, 0);
            a = __builtin_amdgcn_mfma_f32_16x16x32_bf16(aY1, *(const bf16x8*)&Wtab[2][nt * 2 + 1][l][0], a, 0, 0, 0);
            acc[nt] = a;
        }

        // ---- scatter into LDS accumulators (ds_add_f32, no vmcnt involvement)
#pragma unroll
        for (int jj = 0; jj < 4; ++jj) {
            const bool v = (eBase + lg * 4 + jj) < R1;
            const int dl = dlocD[jj];
#pragma unroll
            for (int nt = 0; nt < 4; ++nt) {
                float ex = v ? __expf(silu_f(acc[nt][jj])) : 0.0f;
                atomicAdd(&accS[0][dl][nt * 16 + lm], ex);
                atomicAdd(&accS[1][dl][nt * 16 + lm], ex * ((float)vcur[jj][nt] + (float)dltb[nt][jj]));
            }
        }
    }

    __syncthreads();
    // ---- flush: pre = num / den for this block's DPB nodes
#pragma unroll
    for (int idx = t; idx < DPB * 64; idx += 256) {
        int dl = idx >> 6, ch = idx & 63;
        int node = D0 + dl;
        if (node < N) {
            float den = accS[0][dl][ch];
            float num = accS[1][dl][ch];
            pre[(size_t)node * 64 + ch] = num / den;
        }
    }
}

// ---------------------------------------------------------------------------
// Kernel: o = pre @ Wout + bout ; accumulate BN2 stats
// ---------------------------------------------------------------------------
__global__ __launch_bounds__(256) void k_out(
    const float* __restrict__ pre,
    const float* __restrict__ Wout, const float* __restrict__ bout,
    float* __restrict__ o, float* __restrict__ ssum, float* __restrict__ ssq, int N)
{
    __shared__ float xt[64 * 64];
    __shared__ float Wl[64 * 64];
    __shared__ float red[2][4][64];
    const int t = threadIdx.x, c = t & 63, g = t >> 6;
    const int row0 = blockIdx.x * 64;

    for (int i = t; i < 64 * 64; i += 256) {
        int r = i >> 6, cc = i & 63;
        int gr = row0 + r;
        xt[i] = (gr < N) ? pre[(size_t)gr * CH + cc] : 0.0f;
        Wl[i] = Wout[i];
    }
    __syncthreads();

    float acc[16];
    const float b = bout[c];
#pragma unroll
    for (int i = 0; i < 16; ++i) acc[i] = b;
    for (int k = 0; k < 64; ++k) {
        float w = Wl[k * 64 + c];
#pragma unroll
        for (int i = 0; i < 16; ++i) acc[i] += xt[(g * 16 + i) * 64 + k] * w;
    }
    float s = 0.0f, ss = 0.0f;
#pragma unroll
    for (int i = 0; i < 16; ++i) {
        int gr = row0 + g * 16 + i;
        if (gr < N) {
            o[(size_t)gr * CH + c] = acc[i];
            s += acc[i];
            ss += acc[i] * acc[i];
        }
    }
    red[0][g][c] = s;
    red[1][g][c] = ss;
    __syncthreads();
    if (g == 0) {
        atomicAdd(&ssum[c], red[0][0][c] + red[0][1][c] + red[0][2][c] + red[0][3][c]);
        atomicAdd(&ssq[c],  red[1][0][c] + red[1][1][c] + red[1][2][c] + red[1][3][c]);
    }
}

// ---------------------------------------------------------------------------
__global__ void k_final(const float* __restrict__ o, const float* __restrict__ scale,
                        const float* __restrict__ shift, float* __restrict__ out, int total)
{
    int i = blockIdx.x * blockDim.x + threadIdx.x;
    if (i < total) {
        int c = i & 63;
        out[i] = o[i] * scale[c] + shift[c];
    }
}

// ---------------------------------------------------------------------------
extern "C" void kernel_launch(void* const* d_in, const int* in_sizes, int n_in,
                              void* d_out, int out_size, void* d_ws, size_t ws_size,
                              hipStream_t stream)
{
    const float* x      = (const float*)d_in[0];
    const float* pos    = (const float*)d_in[1];
    const int*   ei     = (const int*)d_in[2];
    const float* Win    = (const float*)d_in[3];
    const float* bin    = (const float*)d_in[4];
    const float* gin    = (const float*)d_in[5];
    const float* betain = (const float*)d_in[6];
    const float* Wv     = (const float*)d_in[7];
    const float* Wk     = (const float*)d_in[8];
    const float* Wq     = (const float*)d_in[9];
    const float* P1     = (const float*)d_in[10];
    const float* pb1    = (const float*)d_in[11];
    const float* P2     = (const float*)d_in[12];
    const float* pb2    = (const float*)d_in[13];
    const float* A1     = (const float*)d_in[14];
    const float* ab1    = (const float*)d_in[15];
    const float* A2     = (const float*)d_in[16];
    const float* ab2    = (const float*)d_in[17];
    const float* Wout   = (const float*)d_in[18];
    const float* bout   = (const float*)d_in[19];
    const float* gout   = (const float*)d_in[20];
    const float* betaout= (const float*)d_in[21];

    const int N = in_sizes[0] / CH;
    const int E = in_sizes[2] / 2;
    const int Etot = E + N;
    const int* srcA = ei;
    const int* dstA = ei + E;

    float* ws = (float*)d_ws;
    const size_t NC = (size_t)N * CH;
    float* h      = ws;                 // N*C f32 (reused as o after edge pass)
    float* pre    = h + NC;             // N*C f32
    float* st     = pre + NC;           // 512 f32 stats
    int*   cnt    = (int*)(st + 512);   // N (zeroed with st)
    int*   exc    = cnt + N;            // N
    int*   rowptr = exc + N;            // N
    int*   cur    = rowptr + N;         // N
    int*   bsum   = cur + N;            // 256
    int2*  sortedSD = (int2*)(bsum + 256);        // Etot int2
    __bf16* vvb = (__bf16*)(sortedSD + Etot);     // N*C bf16
    __bf16* kkb = vvb + NC;                       // N*C bf16
    __bf16* qqb = kkb + NC;                       // N*C bf16

    // zero stats + cnt (contiguous)
    hipMemsetAsync(st, 0, (512 + (size_t)N) * sizeof(float), stream);

    // ---- counting sort by dst
    const int nbScan = (N + 1023) / 1024;
    k_hist<<<(Etot + 255) / 256, 256, 0, stream>>>(dstA, cnt, E, Etot);
    k_scan_a<<<nbScan, 256, 0, stream>>>(cnt, exc, bsum, N);
    k_scan_b<<<1, 256, 0, stream>>>(bsum, nbScan);
    k_scan_c<<<(N + 255) / 256, 256, 0, stream>>>(exc, bsum, rowptr, cur, N);
    k_scatter<<<(Etot + 255) / 256, 256, 0, stream>>>(srcA, dstA, cur, sortedSD, E, Etot);

    // ---- node pipeline
    const int nb = (N + 63) / 64;
    k_lin_in<<<nb, 256, 0, stream>>>(x, Win, bin, h, st, st + 64, N);
    k_stats<<<1, 64, 0, stream>>>(st, st + 64, gin, betain, st + 128, st + 192, N);
    k_vkq<<<nb, 256, 0, stream>>>(h, st + 128, st + 192, Wv, Wk, Wq, vvb, kkb, qqb, N);

    // ---- dst-grouped edge pass, LDS accumulation, no global atomics
    const int nBlk = (N + DPB - 1) / DPB;
    k_edge_grp<<<nBlk, 256, 0, stream>>>(sortedSD, rowptr, pos, vvb, kkb, qqb,
                                         P1, pb1, P2, pb2, A1, ab1, A2, ab2,
                                         pre, N, Etot);

    k_out<<<nb, 256, 0, stream>>>(pre, Wout, bout, h, st + 256, st + 320, N);
    k_stats<<<1, 64, 0, stream>>>(st + 256, st + 320, gout, betaout, st + 384, st + 448, N);
    k_final<<<(int)((NC + 255) / 256), 256, 0, stream>>>(h, st + 384, st + 448,
                                                         (float*)d_out, (int)NC);
}

// Round 9
// 523.269 us; speedup vs baseline: 2.1165x; 2.1165x over previous
//
#include <hip/hip_runtime.h>

#define CH 64
#define BN_EPS 1e-5f

typedef __attribute__((ext_vector_type(8))) __bf16 bf16x8;
typedef __attribute__((ext_vector_type(4))) __bf16 bf16x4;
typedef __attribute__((ext_vector_type(4))) float f32x4;

__device__ __forceinline__ float silu_f(float x) { return x / (1.0f + __expf(-x)); }

// ---------------------------------------------------------------------------
// Kernel: h = x @ Win + bin ; accumulate per-channel sum/sumsq for BN1
// ---------------------------------------------------------------------------
__global__ __launch_bounds__(256) void k_lin_in(
    const float* __restrict__ x, const float* __restrict__ Win, const float* __restrict__ bin,
    float* __restrict__ h, float* __restrict__ ssum, float* __restrict__ ssq, int N)
{
    __shared__ float xt[64 * 64];
    __shared__ float Wl[64 * 64];
    __shared__ float red[2][4][64];
    const int t = threadIdx.x, c = t & 63, g = t >> 6;
    const int row0 = blockIdx.x * 64;

    for (int i = t; i < 64 * 64; i += 256) {
        int r = i >> 6, cc = i & 63;
        int gr = row0 + r;
        xt[i] = (gr < N) ? x[(size_t)gr * CH + cc] : 0.0f;
        Wl[i] = Win[i];
    }
    __syncthreads();

    float acc[16];
    const float b = bin[c];
#pragma unroll
    for (int i = 0; i < 16; ++i) acc[i] = b;
    for (int k = 0; k < 64; ++k) {
        float w = Wl[k * 64 + c];
#pragma unroll
        for (int i = 0; i < 16; ++i) acc[i] += xt[(g * 16 + i) * 64 + k] * w;
    }
    float s = 0.0f, ss = 0.0f;
#pragma unroll
    for (int i = 0; i < 16; ++i) {
        int gr = row0 + g * 16 + i;
        if (gr < N) {
            h[(size_t)gr * CH + c] = acc[i];
            s += acc[i];
            ss += acc[i] * acc[i];
        }
    }
    red[0][g][c] = s;
    red[1][g][c] = ss;
    __syncthreads();
    if (g == 0) {
        atomicAdd(&ssum[c], red[0][0][c] + red[0][1][c] + red[0][2][c] + red[0][3][c]);
        atomicAdd(&ssq[c],  red[1][0][c] + red[1][1][c] + red[1][2][c] + red[1][3][c]);
    }
}

// ---------------------------------------------------------------------------
__global__ void k_stats(const float* __restrict__ ssum, const float* __restrict__ ssq,
                        const float* __restrict__ gamma, const float* __restrict__ beta,
                        float* __restrict__ scale, float* __restrict__ shift, int N)
{
    int c = threadIdx.x;
    float inv = 1.0f / (float)N;
    float mu = ssum[c] * inv;
    float var = ssq[c] * inv - mu * mu;
    float sc = gamma[c] * rsqrtf(var + BN_EPS);
    scale[c] = sc;
    shift[c] = beta[c] - mu * sc;
}

// ---------------------------------------------------------------------------
// Kernel: pos4[i] = (pos[3i], pos[3i+1], pos[3i+2], 0)
// ---------------------------------------------------------------------------
__global__ void k_pos4(const float* __restrict__ pos, float4* __restrict__ pos4, int N)
{
    int i = blockIdx.x * blockDim.x + threadIdx.x;
    if (i < N) pos4[i] = make_float4(pos[3 * i], pos[3 * i + 1], pos[3 * i + 2], 0.0f);
}

// ---------------------------------------------------------------------------
// Kernel: x1 = silu(h*scale+shift); v/k/q = x1@W — stored as bf16
// ---------------------------------------------------------------------------
__global__ __launch_bounds__(256) void k_vkq(
    const float* __restrict__ h, const float* __restrict__ scale, const float* __restrict__ shift,
    const float* __restrict__ Wv, const float* __restrict__ Wk, const float* __restrict__ Wq,
    __bf16* __restrict__ vv, __bf16* __restrict__ kk, __bf16* __restrict__ qq, int N)
{
    __shared__ float xt[64 * 64];
    __shared__ float Wl[2][64 * 64];
    const int t = threadIdx.x, c = t & 63, g = t >> 6;
    const int row0 = blockIdx.x * 64;

    for (int i = t; i < 64 * 64; i += 256) {
        int r = i >> 6, cc = i & 63;
        int gr = row0 + r;
        float hv = (gr < N) ? h[(size_t)gr * CH + cc] : 0.0f;
        xt[i] = silu_f(hv * scale[cc] + shift[cc]);
        Wl[0][i] = Wv[i];
        Wl[1][i] = Wk[i];
    }
    __syncthreads();

    for (int m = 0; m < 2; ++m) {
        float acc[16];
#pragma unroll
        for (int i = 0; i < 16; ++i) acc[i] = 0.0f;
        for (int k = 0; k < 64; ++k) {
            float w = Wl[m][k * 64 + c];
#pragma unroll
            for (int i = 0; i < 16; ++i) acc[i] += xt[(g * 16 + i) * 64 + k] * w;
        }
        __bf16* o = (m == 0) ? vv : kk;
#pragma unroll
        for (int i = 0; i < 16; ++i) {
            int gr = row0 + g * 16 + i;
            if (gr < N) o[(size_t)gr * CH + c] = (__bf16)acc[i];
        }
    }
    __syncthreads();
    for (int i = t; i < 64 * 64; i += 256) Wl[0][i] = Wq[i];
    __syncthreads();
    {
        float acc[16];
#pragma unroll
        for (int i = 0; i < 16; ++i) acc[i] = 0.0f;
        for (int k = 0; k < 64; ++k) {
            float w = Wl[0][k * 64 + c];
#pragma unroll
            for (int i = 0; i < 16; ++i) acc[i] += xt[(g * 16 + i) * 64 + k] * w;
        }
#pragma unroll
        for (int i = 0; i < 16; ++i) {
            int gr = row0 + g * 16 + i;
            if (gr < N) qq[(size_t)gr * CH + c] = (__bf16)acc[i];
        }
    }
}

// ---------------------------------------------------------------------------
// MFMA edge kernel, software-pipelined (R3/R6 proven structure).
// Index loads 2-ahead; pos/qk gathers 1-ahead; v gathers at body top.
// P1 layer computed on VALU directly in A-layout (t1[row=lm][k] depends only
// on this lane's own pos-delta) — saves 4 MFMAs + one LDS roundtrip.
// ---------------------------------------------------------------------------
__global__ __launch_bounds__(256) void k_edge_mfma(
    const int* __restrict__ srcA, const int* __restrict__ dstA,
    const float4* __restrict__ pos4,
    const __bf16* __restrict__ vvb, const __bf16* __restrict__ kkb, const __bf16* __restrict__ qqb,
    const float* __restrict__ P1, const float* __restrict__ pb1,
    const float* __restrict__ P2, const float* __restrict__ pb2,
    const float* __restrict__ A1, const float* __restrict__ ab1,
    const float* __restrict__ A2, const float* __restrict__ ab2,
    float* __restrict__ num, float* __restrict__ den,
    int E, int Etot, int nChunks)
{
    __shared__ __align__(16) __bf16 Wtab[3][8][64][8];   // 24.0 KiB
    __shared__ __align__(16) __bf16 tb[4][16][66];       //  8.25 KiB
    __shared__ __align__(16) __bf16 P1L[3][64];          //  384 B
    __shared__ __align__(16) float pb1L[64];             //  256 B

    const int t = threadIdx.x;
    for (int i = t; i < 3 * 4096; i += 256) {
        int mat = i >> 12, r = i & 4095;
        int j = r & 7, lane = (r >> 3) & 63, ksnt = r >> 9;
        int ks = ksnt & 1, nt = ksnt >> 1;
        int k = ks * 32 + ((lane >> 4) & 3) * 8 + j;
        int n = nt * 16 + (lane & 15);
        const float* W = (mat == 0) ? P2 : ((mat == 1) ? A1 : A2);
        Wtab[mat][ksnt][lane][j] = (__bf16)W[k * 64 + n];
    }
    if (t < 192) P1L[t / 64][t & 63] = (__bf16)P1[t];
    if (t < 64)  pb1L[t] = pb1[t];
    __syncthreads();

    const int l = t & 63, wid = t >> 6, lg = l >> 4, lm = l & 15;
    __bf16* tbw = &tb[wid][0][0];

    float pb2r[4], ab1r[4], ab2r[4];
#pragma unroll
    for (int nt = 0; nt < 4; ++nt) {
        int co = nt * 16 + lm;
        pb2r[nt] = pb2[co];
        ab1r[nt] = ab1[co]; ab2r[nt] = ab2[co];
    }

    const int stride = gridDim.x;
    int ch = blockIdx.x;
    if (ch >= nChunks) return;

    // ---- prologue: indices + gathers for chunk0, indices for chunk1
    int sC = 0, dC = 0;
    {
        int eA = ch * 64 + wid * 16 + lm;
        if (eA < Etot) { if (eA < E) { sC = srcA[eA]; dC = dstA[eA]; } else { sC = dC = eA - E; } }
    }
    float pdl0, pdl1, pdl2;
    bf16x8 qmk0, qmk1;
    {
        float4 ps4 = pos4[sC], pd4 = pos4[dC];
        pdl0 = pd4.x - ps4.x; pdl1 = pd4.y - ps4.y; pdl2 = pd4.z - ps4.z;
        const __bf16* qp = qqb + (size_t)dC * 64 + lg * 8;
        const __bf16* kp = kkb + (size_t)sC * 64 + lg * 8;
        bf16x8 q0 = *(const bf16x8*)qp, q1 = *(const bf16x8*)(qp + 32);
        bf16x8 k0 = *(const bf16x8*)kp, k1 = *(const bf16x8*)(kp + 32);
#pragma unroll
        for (int j = 0; j < 8; ++j) {
            qmk0[j] = (__bf16)((float)q0[j] - (float)k0[j]);
            qmk1[j] = (__bf16)((float)q1[j] - (float)k1[j]);
        }
    }
    int chn = ch + stride;
    bool hn = chn < nChunks;
    int sN = 0, dN = 0;
    if (hn) {
        int eA = chn * 64 + wid * 16 + lm;
        if (eA < Etot) { if (eA < E) { sN = srcA[eA]; dN = dstA[eA]; } else { sN = dN = eA - E; } }
    }

    for (;;) {
        const int e0 = ch * 64 + wid * 16;

        // ---- stage B: v gathers for current (consumed at scatter, end of body)
        int dD[4];
        __bf16 vcur[4][4];
#pragma unroll
        for (int jj = 0; jj < 4; ++jj) {
            int sD = __shfl(sC, lg * 4 + jj);
            dD[jj] = __shfl(dC, lg * 4 + jj);
            const __bf16* vp = vvb + (size_t)sD * 64 + lm;
#pragma unroll
            for (int nt = 0; nt < 4; ++nt) vcur[jj][nt] = vp[nt * 16];
        }

        // ---- P1 layer on VALU, directly in A-layout (edge row = own lane lm)
        bf16x8 aX0, aX1;
#pragma unroll
        for (int f = 0; f < 2; ++f) {
            const int k0i = f * 32 + lg * 8;
            bf16x8 w0 = *(const bf16x8*)&P1L[0][k0i];
            bf16x8 w1 = *(const bf16x8*)&P1L[1][k0i];
            bf16x8 w2 = *(const bf16x8*)&P1L[2][k0i];
            f32x4 b0 = *(const f32x4*)&pb1L[k0i];
            f32x4 b1 = *(const f32x4*)&pb1L[k0i + 4];
#pragma unroll
            for (int j = 0; j < 8; ++j) {
                float bb = (j < 4) ? b0[j & 3] : b1[j & 3];
                float tv = silu_f(pdl0 * (float)w0[j] + pdl1 * (float)w1[j] +
                                  pdl2 * (float)w2[j] + bb);
                if (f == 0) aX0[j] = (__bf16)tv; else aX1[j] = (__bf16)tv;
            }
        }

        // ---- P2 (MFMA)
        f32x4 acc[4];
#pragma unroll
        for (int nt = 0; nt < 4; ++nt) {
            f32x4 a; a[0] = a[1] = a[2] = a[3] = pb2r[nt];
            a = __builtin_amdgcn_mfma_f32_16x16x32_bf16(aX0, *(const bf16x8*)&Wtab[0][nt * 2 + 0][l][0], a, 0, 0, 0);
            a = __builtin_amdgcn_mfma_f32_16x16x32_bf16(aX1, *(const bf16x8*)&Wtab[0][nt * 2 + 1][l][0], a, 0, 0, 0);
            acc[nt] = a;
        }
        bf16x4 dltb[4];
#pragma unroll
        for (int nt = 0; nt < 4; ++nt)
#pragma unroll
            for (int jj = 0; jj < 4; ++jj) {
                float dv = silu_f(acc[nt][jj]);
                dltb[nt][jj] = (__bf16)dv;
                tbw[(lg * 4 + jj) * 66 + nt * 16 + lm] = (__bf16)dv;
            }

        // ---- stage C: next-chunk gathers (pos-delta + q-k), hide under A1/A2
        float pdlN0 = 0.f, pdlN1 = 0.f, pdlN2 = 0.f;
        bf16x8 qmkN0, qmkN1;
        if (hn) {
            float4 ps4 = pos4[sN], pd4 = pos4[dN];
            pdlN0 = pd4.x - ps4.x; pdlN1 = pd4.y - ps4.y; pdlN2 = pd4.z - ps4.z;
            const __bf16* qp = qqb + (size_t)dN * 64 + lg * 8;
            const __bf16* kp = kkb + (size_t)sN * 64 + lg * 8;
            bf16x8 q0 = *(const bf16x8*)qp, q1 = *(const bf16x8*)(qp + 32);
            bf16x8 k0 = *(const bf16x8*)kp, k1 = *(const bf16x8*)(kp + 32);
#pragma unroll
            for (int j = 0; j < 8; ++j) {
                qmkN0[j] = (__bf16)((float)q0[j] - (float)k0[j]);
                qmkN1[j] = (__bf16)((float)q1[j] - (float)k1[j]);
            }
        }

        // ---- prefetch indices 2 chunks ahead
        const int chn2 = chn + stride;
        const bool hn2 = hn && (chn2 < nChunks);
        int sNN = 0, dNN = 0;
        if (hn2) {
            int eA = chn2 * 64 + wid * 16 + lm;
            if (eA < Etot) { if (eA < E) { sNN = srcA[eA]; dNN = dstA[eA]; } else { sNN = dNN = eA - E; } }
        }

        // ---- alpha0 = (q-k) + delta  (delta re-read in A-layout)
        bf16x8 dA0 = *(const bf16x8*)&tbw[lm * 66 + lg * 8];
        bf16x8 dA1 = *(const bf16x8*)&tbw[lm * 66 + 32 + lg * 8];
        bf16x8 aA0, aA1;
#pragma unroll
        for (int j = 0; j < 8; ++j) {
            aA0[j] = (__bf16)((float)qmk0[j] + (float)dA0[j]);
            aA1[j] = (__bf16)((float)qmk1[j] + (float)dA1[j]);
        }

        // ---- A1
#pragma unroll
        for (int nt = 0; nt < 4; ++nt) {
            f32x4 a; a[0] = a[1] = a[2] = a[3] = ab1r[nt];
            a = __builtin_amdgcn_mfma_f32_16x16x32_bf16(aA0, *(const bf16x8*)&Wtab[1][nt * 2 + 0][l][0], a, 0, 0, 0);
            a = __builtin_amdgcn_mfma_f32_16x16x32_bf16(aA1, *(const bf16x8*)&Wtab[1][nt * 2 + 1][l][0], a, 0, 0, 0);
            acc[nt] = a;
        }
#pragma unroll
        for (int nt = 0; nt < 4; ++nt)
#pragma unroll
            for (int jj = 0; jj < 4; ++jj)
                tbw[(lg * 4 + jj) * 66 + nt * 16 + lm] = (__bf16)silu_f(acc[nt][jj]);
        bf16x8 aY0 = *(const bf16x8*)&tbw[lm * 66 + lg * 8];
        bf16x8 aY1 = *(const bf16x8*)&tbw[lm * 66 + 32 + lg * 8];

        // ---- A2
#pragma unroll
        for (int nt = 0; nt < 4; ++nt) {
            f32x4 a; a[0] = a[1] = a[2] = a[3] = ab2r[nt];
            a = __builtin_amdgcn_mfma_f32_16x16x32_bf16(aY0, *(const bf16x8*)&Wtab[2][nt * 2 + 0][l][0], a, 0, 0, 0);
            a = __builtin_amdgcn_mfma_f32_16x16x32_bf16(aY1, *(const bf16x8*)&Wtab[2][nt * 2 + 1][l][0], a, 0, 0, 0);
            acc[nt] = a;
        }

        // ---- scatter: lane covers co = nt*16+lm for edge er = lg*4+jj
#pragma unroll
        for (int jj = 0; jj < 4; ++jj) {
            const int eD = e0 + lg * 4 + jj;
            const bool v = eD < Etot;
            const size_t ob = (size_t)dD[jj] * 64 + lm;
#pragma unroll
            for (int nt = 0; nt < 4; ++nt) {
                float ex = v ? __expf(silu_f(acc[nt][jj])) : 0.0f;
                atomicAdd(&den[ob + nt * 16], ex);
                atomicAdd(&num[ob + nt * 16], ex * ((float)vcur[jj][nt] + (float)dltb[nt][jj]));
            }
        }

        if (!hn) break;
        ch = chn; chn = chn2; hn = hn2;
        sC = sN; dC = dN; sN = sNN; dN = dNN;
        pdl0 = pdlN0; pdl1 = pdlN1; pdl2 = pdlN2;
        qmk0 = qmkN0; qmk1 = qmkN1;
    }
}

// ---------------------------------------------------------------------------
// Kernel: pre = num/den; o = pre @ Wout + bout ; accumulate BN2 stats
// ---------------------------------------------------------------------------
__global__ __launch_bounds__(256) void k_out(
    const float* __restrict__ num, const float* __restrict__ den,
    const float* __restrict__ Wout, const float* __restrict__ bout,
    float* __restrict__ o, float* __restrict__ ssum, float* __restrict__ ssq, int N)
{
    __shared__ float xt[64 * 64];
    __shared__ float Wl[64 * 64];
    __shared__ float red[2][4][64];
    const int t = threadIdx.x, c = t & 63, g = t >> 6;
    const int row0 = blockIdx.x * 64;

    for (int i = t; i < 64 * 64; i += 256) {
        int r = i >> 6, cc = i & 63;
        int gr = row0 + r;
        xt[i] = (gr < N) ? num[(size_t)gr * CH + cc] / den[(size_t)gr * CH + cc] : 0.0f;
        Wl[i] = Wout[i];
    }
    __syncthreads();

    float acc[16];
    const float b = bout[c];
#pragma unroll
    for (int i = 0; i < 16; ++i) acc[i] = b;
    for (int k = 0; k < 64; ++k) {
        float w = Wl[k * 64 + c];
#pragma unroll
        for (int i = 0; i < 16; ++i) acc[i] += xt[(g * 16 + i) * 64 + k] * w;
    }
    float s = 0.0f, ss = 0.0f;
#pragma unroll
    for (int i = 0; i < 16; ++i) {
        int gr = row0 + g * 16 + i;
        if (gr < N) {
            o[(size_t)gr * CH + c] = acc[i];
            s += acc[i];
            ss += acc[i] * acc[i];
        }
    }
    red[0][g][c] = s;
    red[1][g][c] = ss;
    __syncthreads();
    if (g == 0) {
        atomicAdd(&ssum[c], red[0][0][c] + red[0][1][c] + red[0][2][c] + red[0][3][c]);
        atomicAdd(&ssq[c],  red[1][0][c] + red[1][1][c] + red[1][2][c] + red[1][3][c]);
    }
}

// ---------------------------------------------------------------------------
__global__ void k_final(const float* __restrict__ o, const float* __restrict__ scale,
                        const float* __restrict__ shift, float* __restrict__ out, int total)
{
    int i = blockIdx.x * blockDim.x + threadIdx.x;
    if (i < total) {
        int c = i & 63;
        out[i] = o[i] * scale[c] + shift[c];
    }
}

// ---------------------------------------------------------------------------
extern "C" void kernel_launch(void* const* d_in, const int* in_sizes, int n_in,
                              void* d_out, int out_size, void* d_ws, size_t ws_size,
                              hipStream_t stream)
{
    const float* x      = (const float*)d_in[0];
    const float* pos    = (const float*)d_in[1];
    const int*   ei     = (const int*)d_in[2];
    const float* Win    = (const float*)d_in[3];
    const float* bin    = (const float*)d_in[4];
    const float* gin    = (const float*)d_in[5];
    const float* betain = (const float*)d_in[6];
    const float* Wv     = (const float*)d_in[7];
    const float* Wk     = (const float*)d_in[8];
    const float* Wq     = (const float*)d_in[9];
    const float* P1     = (const float*)d_in[10];
    const float* pb1    = (const float*)d_in[11];
    const float* P2     = (const float*)d_in[12];
    const float* pb2    = (const float*)d_in[13];
    const float* A1     = (const float*)d_in[14];
    const float* ab1    = (const float*)d_in[15];
    const float* A2     = (const float*)d_in[16];
    const float* ab2    = (const float*)d_in[17];
    const float* Wout   = (const float*)d_in[18];
    const float* bout   = (const float*)d_in[19];
    const float* gout   = (const float*)d_in[20];
    const float* betaout= (const float*)d_in[21];

    const int N = in_sizes[0] / CH;
    const int E = in_sizes[2] / 2;
    const int Etot = E + N;
    const int* srcA = ei;
    const int* dstA = ei + E;

    float* ws = (float*)d_ws;
    const size_t NC = (size_t)N * CH;
    float* h     = ws;                   // N*C f32 (reused as o after edge pass)
    float* num   = h + NC;               // N*C f32
    float* den   = num + NC;             // N*C f32
    float* st    = den + NC;             // 512 f32 stats
    float4* pos4 = (float4*)(st + 512);  // N float4
    __bf16* vvb  = (__bf16*)(pos4 + N);  // N*C bf16
    __bf16* kkb  = vvb + NC;             // N*C bf16
    __bf16* qqb  = kkb + NC;             // N*C bf16

    // zero num, den, stats in one shot (contiguous)
    hipMemsetAsync(num, 0, (2 * NC + 512) * sizeof(float), stream);

    const int nb = (N + 63) / 64;
    k_pos4<<<(N + 255) / 256, 256, 0, stream>>>(pos, pos4, N);
    k_lin_in<<<nb, 256, 0, stream>>>(x, Win, bin, h, st, st + 64, N);
    k_stats<<<1, 64, 0, stream>>>(st, st + 64, gin, betain, st + 128, st + 192, N);
    k_vkq<<<nb, 256, 0, stream>>>(h, st + 128, st + 192, Wv, Wk, Wq, vvb, kkb, qqb, N);

    const int nChunks = (Etot + 63) / 64;
    const int grid = (nChunks < 2048) ? nChunks : 2048;
    k_edge_mfma<<<grid, 256, 0, stream>>>(srcA, dstA, pos4, vvb, kkb, qqb,
                                          P1, pb1, P2, pb2, A1, ab1, A2, ab2,
                                          num, den, E, Etot, nChunks);

    k_out<<<nb, 256, 0, stream>>>(num, den, Wout, bout, h, st + 256, st + 320, N);
    k_stats<<<1, 64, 0, stream>>>(st + 256, st + 320, gout, betaout, st + 384, st + 448, N);
    k_final<<<(int)((NC + 255) / 256), 256, 0, stream>>>(h, st + 384, st + 448,
                                                         (float*)d_out, (int)NC);
}